// Round 6
// baseline (527.977 us; speedup 1.0000x reference)
//
#include <hip/hip_runtime.h>

#define BATCH   200000
#define NSTEP   4
#define NTP     (2 * NSTEP + 1)   // distinct time points for RK4
#define TPB     64

// FOLD_C = -2*log2(e): folded into stored weights so r = rcp(1+exp2(z.ws+bs)) = sigmoid(2*pre)
#define FOLD_C  (-2.885390081777927f)
#define LOG2E   (1.4426950408889634f)

typedef float v2f __attribute__((ext_vector_type(2)));
typedef float v4f __attribute__((ext_vector_type(4)));

__device__ __forceinline__ float fast_tanh(float x) {
    float q = __builtin_amdgcn_exp2f(FOLD_C * x);          // exp(-2x)
    return 2.0f * __builtin_amdgcn_rcpf(1.0f + q) - 1.0f;
}
__device__ __forceinline__ float fast_sigmoid(float x) {
    return __builtin_amdgcn_rcpf(1.0f + __builtin_amdgcn_exp2f(-LOG2E * x));
}

// One dynamics eval for one element, params in LDS (uniform-address broadcast reads).
// Per-tp layout (384 floats): [0:128) W pairs {w0_2m,w0_2m+1,w1_2m,w1_2m+1},
// [128:256) {b_2m,b_2m+1,4wu_2m,4wu_2m+1}, [256:384) {2u0 pair, 2u1 pair}.
// r = sigmoid(2*pre); d = -dz = (su - sum r*2u)/64 ; dl = +tr = (sum (r-r^2)*4wu)/64
__device__ __forceinline__ void feval(const float* P, float sux, float suy,
                                      float z0, float z1,
                                      float& d0, float& d1, float& dl) {
    const v4f* Wp = (const v4f*)(P);
    const v4f* Bp = (const v4f*)(P + 128);
    const v4f* Up = (const v4f*)(P + 256);

    const v2f vz0 = {z0, z0};
    const v2f vz1 = {z1, z1};
    const v2f one = {1.0f, 1.0f};

    v2f a0 = {0.0f, 0.0f}, a1 = {0.0f, 0.0f}, tt = {0.0f, 0.0f};
    #pragma unroll 8
    for (int m = 0; m < 32; ++m) {
        const v4f A = Wp[m];
        const v4f B = Bp[m];
        const v4f U = Up[m];
        const v2f w0 = __builtin_shufflevector(A, A, 0, 1);
        const v2f w1 = __builtin_shufflevector(A, A, 2, 3);
        const v2f bb = __builtin_shufflevector(B, B, 0, 1);
        const v2f wu = __builtin_shufflevector(B, B, 2, 3);
        const v2f u0 = __builtin_shufflevector(U, U, 0, 1);
        const v2f u1 = __builtin_shufflevector(U, U, 2, 3);

        const v2f p = __builtin_elementwise_fma(vz0, w0,
                      __builtin_elementwise_fma(vz1, w1, bb));
        v2f q;
        q.x = __builtin_amdgcn_exp2f(p.x);
        q.y = __builtin_amdgcn_exp2f(p.y);
        const v2f qp = q + one;
        v2f r;
        r.x = __builtin_amdgcn_rcpf(qp.x);
        r.y = __builtin_amdgcn_rcpf(qp.y);
        a0 = __builtin_elementwise_fma(r, u0, a0);
        a1 = __builtin_elementwise_fma(r, u1, a1);
        const v2f rm = __builtin_elementwise_fma(-r, r, r);
        tt = __builtin_elementwise_fma(rm, wu, tt);
    }
    const float inv = 1.0f / 64.0f;
    d0 = (sux - (a0.x + a0.y)) * inv;
    d1 = (suy - (a1.x + a1.y)) * inv;
    dl = (tt.x + tt.y) * inv;
}

__global__ __launch_bounds__(TPB, 4)
void cnf_fused(const float2* __restrict__ x2, const float* __restrict__ lp_in,
               const float* __restrict__ fc1_w, const float* __restrict__ fc1_b,
               const float* __restrict__ fc2_w, const float* __restrict__ fc2_b,
               const float* __restrict__ fc3_w, const float* __restrict__ fc3_b,
               float* __restrict__ out) {
    __shared__ __align__(16) float sP[NTP * 384];   // packed params per timepoint
    __shared__ float p3s[448];                      // fc3 output scratch; [0:64) doubles as p1
    __shared__ float p2s[64];
    __shared__ float sH[NTP][2];                    // (sum u0, sum u1) per tp

    const int j = threadIdx.x;

    // ---- phase 1: hypernet for all NTP timepoints (redundant per block) ----
    for (int idx = 0; idx < NTP; ++idx) {
        const float t = 1.0f - (float)idx * (0.5f / (float)NSTEP);   // t = T1 - s

        p3s[j] = fast_tanh(fmaf(fc1_w[j], t, fc1_b[j]));   // p1 in p3s[0:64)
        __syncthreads();

        float acc = fc2_b[j];
        #pragma unroll 16
        for (int k = 0; k < 64; ++k) acc = fmaf(fc2_w[j * 64 + k], p3s[k], acc);
        p2s[j] = fast_tanh(acc);
        __syncthreads();                 // p1 reads done (acc final) + p2 visible

        #pragma unroll
        for (int r = 0; r < 7; ++r) {    // 448 outputs; r=0 overwrites dead p1 region
            const int m = j + r * 64;
            float a = fc3_b[m];
            #pragma unroll 16
            for (int k = 0; k < 64; ++k) a = fmaf(fc3_w[m * 64 + k], p2s[k], a);
            p3s[m] = a;
        }
        __syncthreads();

        const float w0 = p3s[2 * j];
        const float w1 = p3s[2 * j + 1];
        const float u0 = p3s[128 + 2 * j]     * fast_sigmoid(p3s[256 + 2 * j]);
        const float u1 = p3s[128 + 2 * j + 1] * fast_sigmoid(p3s[256 + 2 * j + 1]);
        const float bb = p3s[384 + j];
        const float wu = w0 * u0 + w1 * u1;

        float* P = sP + idx * 384;
        const int m = j >> 1, p = j & 1;
        P[4 * m + p]           = FOLD_C * w0;
        P[4 * m + 2 + p]       = FOLD_C * w1;
        P[128 + 4 * m + p]     = FOLD_C * bb;
        P[128 + 4 * m + 2 + p] = 4.0f * wu;
        P[256 + 4 * m + p]     = 2.0f * u0;
        P[256 + 4 * m + 2 + p] = 2.0f * u1;

        float s0 = u0, s1 = u1;
        #pragma unroll
        for (int o = 32; o > 0; o >>= 1) {
            s0 += __shfl_xor(s0, o);
            s1 += __shfl_xor(s1, o);
        }
        if (j == 0) { sH[idx][0] = s0; sH[idx][1] = s1; }
        __syncthreads();                 // transform reads done before next idx reuses p3s
    }

    // ---- phase 2: RK4 integration, one element per thread ----
    const int n = blockIdx.x * TPB + j;  // grid*TPB == BATCH exactly
    const float2 v = x2[n];
    float z0 = v.x, z1 = v.y, lp = lp_in[n];

    const float hs = 1.0f / (float)NSTEP;

    for (int i = 0; i < NSTEP; ++i) {
        const float* P0 = sP + (2 * i) * 384;       // tp 2i, 2i+1, 2i+2
        const float* P1 = P0 + 384;
        const float* P2 = P0 + 768;
        const float su0x = sH[2 * i][0],     su0y = sH[2 * i][1];
        const float su1x = sH[2 * i + 1][0], su1y = sH[2 * i + 1][1];
        const float su2x = sH[2 * i + 2][0], su2y = sH[2 * i + 2][1];

        float k10, k11, k1l, k20, k21, k2l, k30, k31, k3l, k40, k41, k4l;
        feval(P0, su0x, su0y, z0, z1, k10, k11, k1l);
        feval(P1, su1x, su1y, fmaf(0.5f*hs, k10, z0), fmaf(0.5f*hs, k11, z1), k20, k21, k2l);
        feval(P1, su1x, su1y, fmaf(0.5f*hs, k20, z0), fmaf(0.5f*hs, k21, z1), k30, k31, k3l);
        feval(P2, su2x, su2y, fmaf(hs, k30, z0), fmaf(hs, k31, z1), k40, k41, k4l);

        const float c = hs * (1.0f / 6.0f);
        z0 += c * (k10 + 2.0f * (k20 + k30) + k40);
        z1 += c * (k11 + 2.0f * (k21 + k31) + k41);
        lp += c * (k1l + 2.0f * (k2l + k3l) + k4l);
    }

    float2* outz = (float2*)out;
    outz[n] = make_float2(z0, z1);
    out[2 * BATCH + n] = lp;
}

extern "C" void kernel_launch(void* const* d_in, const int* in_sizes, int n_in,
                              void* d_out, int out_size, void* d_ws, size_t ws_size,
                              hipStream_t stream) {
    const float* x     = (const float*)d_in[0];
    const float* lp_in = (const float*)d_in[1];
    const float* fc1_w = (const float*)d_in[2];
    const float* fc1_b = (const float*)d_in[3];
    const float* fc2_w = (const float*)d_in[4];
    const float* fc2_b = (const float*)d_in[5];
    const float* fc3_w = (const float*)d_in[6];
    const float* fc3_b = (const float*)d_in[7];
    float* out = (float*)d_out;

    // 3125 blocks x 64 threads == 200000 exactly; single fused launch, no d_ws use.
    hipLaunchKernelGGL(cnf_fused, dim3(BATCH / TPB), dim3(TPB), 0, stream,
                       (const float2*)x, lp_in, fc1_w, fc1_b, fc2_w, fc2_b,
                       fc3_w, fc3_b, out);
}

// Round 7
// 140.528 us; speedup vs baseline: 3.7571x; 3.7571x over previous
//
#include <hip/hip_runtime.h>

#define BATCH   200000
#define NSTEP   4
#define NTP     (2 * NSTEP + 1)   // distinct time points for RK4
#define TPB     64

// FOLD_C = -2*log2(e): folded into stored weights so r = rcp(1+exp2(z.ws+bs)) = sigmoid(2*pre)
#define FOLD_C  (-2.885390081777927f)
#define LOG2E   (1.4426950408889634f)

typedef float v2f __attribute__((ext_vector_type(2)));

__device__ __forceinline__ float fast_tanh(float x) {
    float q = __builtin_amdgcn_exp2f(FOLD_C * x);          // exp(-2x)
    return 2.0f * __builtin_amdgcn_rcpf(1.0f + q) - 1.0f;
}
__device__ __forceinline__ float fast_sigmoid(float x) {
    return __builtin_amdgcn_rcpf(1.0f + __builtin_amdgcn_exp2f(-LOG2E * x));
}

// One block per time point, 512 threads. fc3's 448 rows are computed by 448
// threads (64-long dot each) instead of 64 threads x 7 rows: 7x shorter
// dependent-load chain. Field-major packed output per timepoint:
//   P[  0+j]=C*w0  P[ 64+j]=C*w1  P[128+j]=C*b  P[192+j]=2u0  P[256+j]=2u1  P[320+j]=4wu
//   gH[tp] = (sum_j u0, sum_j u1)
__global__ __launch_bounds__(512)
void hypernet_kernel(const float* __restrict__ fc1_w, const float* __restrict__ fc1_b,
                     const float* __restrict__ fc2_w, const float* __restrict__ fc2_b,
                     const float* __restrict__ fc3_w, const float* __restrict__ fc3_b,
                     float* __restrict__ gP, float2* __restrict__ gH) {
    __shared__ float p1s[64];
    __shared__ float p2s[64];
    __shared__ float p3s[448];

    const int tid = threadIdx.x;
    const int idx = blockIdx.x;
    const float t = 1.0f - (float)idx * (0.5f / (float)NSTEP);   // t = T1 - s

    if (tid < 64) p1s[tid] = fast_tanh(fmaf(fc1_w[tid], t, fc1_b[tid]));
    __syncthreads();

    if (tid < 64) {
        float acc = fc2_b[tid];
        #pragma unroll 16
        for (int k = 0; k < 64; ++k) acc = fmaf(fc2_w[tid * 64 + k], p1s[k], acc);
        p2s[tid] = fast_tanh(acc);
    }
    __syncthreads();

    if (tid < 448) {
        float a = fc3_b[tid];
        #pragma unroll 16
        for (int k = 0; k < 64; ++k) a = fmaf(fc3_w[tid * 64 + k], p2s[k], a);
        p3s[tid] = a;
    }
    __syncthreads();

    if (tid < 64) {
        const int j = tid;
        const float w0 = p3s[2 * j];
        const float w1 = p3s[2 * j + 1];
        const float u0 = p3s[128 + 2 * j]     * fast_sigmoid(p3s[256 + 2 * j]);
        const float u1 = p3s[128 + 2 * j + 1] * fast_sigmoid(p3s[256 + 2 * j + 1]);
        const float bb = p3s[384 + j];
        const float wu = w0 * u0 + w1 * u1;

        float* P = gP + idx * 384;
        P[j]       = FOLD_C * w0;
        P[64 + j]  = FOLD_C * w1;
        P[128 + j] = FOLD_C * bb;
        P[192 + j] = 2.0f * u0;
        P[256 + j] = 2.0f * u1;
        P[320 + j] = 4.0f * wu;

        // wave-reduce sum of u0,u1 (threads 0..63 are exactly one wave)
        float s0 = u0, s1 = u1;
        #pragma unroll
        for (int o = 32; o > 0; o >>= 1) {
            s0 += __shfl_xor(s0, o);
            s1 += __shfl_xor(s1, o);
        }
        if (j == 0) gH[idx] = make_float2(s0, s1);
    }
}

// One dynamics eval; j-loop in pairs via packed fp32 (v_pk_fma_f32). Params are
// wave-uniform -> compiler lowers to s_load through the scalar cache.
// r = sigmoid(2*pre); d = -dz = (su - sum r*2u)/64 ; dl = +tr = (sum (r-r^2)*4wu)/64
__device__ __forceinline__ void feval(const float* __restrict__ P,
                                      const float2 su,
                                      float z0, float z1,
                                      float& d0, float& d1, float& dl) {
    const v2f* W0 = (const v2f*)(P);
    const v2f* W1 = (const v2f*)(P + 64);
    const v2f* Bb = (const v2f*)(P + 128);
    const v2f* U0 = (const v2f*)(P + 192);
    const v2f* U1 = (const v2f*)(P + 256);
    const v2f* WU = (const v2f*)(P + 320);

    const v2f vz0 = {z0, z0};
    const v2f vz1 = {z1, z1};
    const v2f one = {1.0f, 1.0f};

    v2f a0 = {0.0f, 0.0f}, a1 = {0.0f, 0.0f}, tt = {0.0f, 0.0f};
    #pragma unroll 8
    for (int m = 0; m < 32; ++m) {
        v2f p = __builtin_elementwise_fma(vz0, W0[m],
                __builtin_elementwise_fma(vz1, W1[m], Bb[m]));
        v2f q;
        q.x = __builtin_amdgcn_exp2f(p.x);
        q.y = __builtin_amdgcn_exp2f(p.y);
        v2f qp = q + one;
        v2f r;
        r.x = __builtin_amdgcn_rcpf(qp.x);
        r.y = __builtin_amdgcn_rcpf(qp.y);
        a0 = __builtin_elementwise_fma(r, U0[m], a0);
        a1 = __builtin_elementwise_fma(r, U1[m], a1);
        v2f rm = __builtin_elementwise_fma(-r, r, r);
        tt = __builtin_elementwise_fma(rm, WU[m], tt);
    }
    const float inv = 1.0f / 64.0f;
    d0 = (su.x - (a0.x + a0.y)) * inv;
    d1 = (su.y - (a1.x + a1.y)) * inv;
    dl = (tt.x + tt.y) * inv;
}

__global__ __launch_bounds__(TPB)
void integrate_kernel(const float2* __restrict__ x2, const float* __restrict__ lp_in,
                      const float* __restrict__ gP, const float2* __restrict__ gH,
                      float* __restrict__ out) {
    const int n = blockIdx.x * TPB + threadIdx.x;   // grid*TPB == BATCH exactly

    float2 v = x2[n];
    float z0 = v.x, z1 = v.y, lp = lp_in[n];

    const float hs = 1.0f / (float)NSTEP;

    for (int i = 0; i < NSTEP; ++i) {
        const float* P0 = gP + (2 * i) * 384;       // tp 2i, 2i+1, 2i+2 contiguous
        const float* P1 = P0 + 384;
        const float* P2 = P0 + 768;
        const float2 su0 = gH[2 * i];
        const float2 su1 = gH[2 * i + 1];
        const float2 su2 = gH[2 * i + 2];

        float k10, k11, k1l, k20, k21, k2l, k30, k31, k3l, k40, k41, k4l;
        feval(P0, su0, z0, z1, k10, k11, k1l);
        feval(P1, su1, fmaf(0.5f*hs, k10, z0), fmaf(0.5f*hs, k11, z1), k20, k21, k2l);
        feval(P1, su1, fmaf(0.5f*hs, k20, z0), fmaf(0.5f*hs, k21, z1), k30, k31, k3l);
        feval(P2, su2, fmaf(hs, k30, z0), fmaf(hs, k31, z1), k40, k41, k4l);

        const float c = hs * (1.0f / 6.0f);
        z0 += c * (k10 + 2.0f * (k20 + k30) + k40);
        z1 += c * (k11 + 2.0f * (k21 + k31) + k41);
        lp += c * (k1l + 2.0f * (k2l + k3l) + k4l);
    }

    float2* outz = (float2*)out;
    outz[n] = make_float2(z0, z1);
    out[2 * BATCH + n] = lp;
}

extern "C" void kernel_launch(void* const* d_in, const int* in_sizes, int n_in,
                              void* d_out, int out_size, void* d_ws, size_t ws_size,
                              hipStream_t stream) {
    const float* x     = (const float*)d_in[0];
    const float* lp_in = (const float*)d_in[1];
    const float* fc1_w = (const float*)d_in[2];
    const float* fc1_b = (const float*)d_in[3];
    const float* fc2_w = (const float*)d_in[4];
    const float* fc2_b = (const float*)d_in[5];
    const float* fc3_w = (const float*)d_in[6];
    const float* fc3_b = (const float*)d_in[7];
    float* out = (float*)d_out;

    // workspace layout: gP (NTP * 384 floats) | gH (NTP float2)
    float*  gP = (float*)d_ws;
    float2* gH = (float2*)((char*)d_ws + NTP * 384 * sizeof(float));

    hipLaunchKernelGGL(hypernet_kernel, dim3(NTP), dim3(512), 0, stream,
                       fc1_w, fc1_b, fc2_w, fc2_b, fc3_w, fc3_b, gP, gH);

    // 3125 blocks x 64 threads == 200000 exactly.
    hipLaunchKernelGGL(integrate_kernel, dim3(BATCH / TPB), dim3(TPB), 0, stream,
                       (const float2*)x, lp_in, gP, gH, out);
}